// Round 8
// baseline (803.752 us; speedup 1.0000x reference)
//
#include <hip/hip_runtime.h>

#define NROW 8192
#define FIN  512
#define FOUT 256
#define ALPHA 0.2f

typedef float  f32x4  __attribute__((ext_vector_type(4)));
typedef int    i32x4  __attribute__((ext_vector_type(4)));
typedef __bf16 bf16x8 __attribute__((ext_vector_type(8)));
typedef __bf16 bf16x4 __attribute__((ext_vector_type(4)));

// ---------------- K1: WbT[f][k] = bf16(W[k][f]) ----------------
__global__ void k1_wt(const float* __restrict__ W, unsigned short* __restrict__ WbT_u) {
    __bf16* WbT = (__bf16*)WbT_u;
    __shared__ float tw[32][33];
    int bx = blockIdx.x & 7;
    int by = blockIdx.x >> 3;
    int f0 = bx * 32, k0 = by * 32;
    int tx = threadIdx.x & 31, ty = threadIdx.x >> 5;
#pragma unroll
    for (int r = 0; r < 4; ++r)
        tw[ty + 8*r][tx] = W[(k0 + ty + 8*r) * FOUT + f0 + tx];
    __syncthreads();
#pragma unroll
    for (int r = 0; r < 4; ++r)
        WbT[(f0 + ty + 8*r) * FIN + k0 + tx] = (__bf16)tw[tx][ty + 8*r];
}

// ---------------- K2: hT[f][i] = sum_k WT[f][k] * x[i][k]  (bf16 MFMA) ----------------
__global__ __launch_bounds__(256, 2) void k2_gemm1(const float* __restrict__ x,
                                                   const unsigned short* __restrict__ WbT_u,
                                                   unsigned short* __restrict__ hTb_u) {
    const __bf16* WbT = (const __bf16*)WbT_u;
    __bf16* hTb = (__bf16*)hTb_u;
    int i0 = blockIdx.x * 32;
    int t = threadIdx.x;
    int lane = t & 63, wv = t >> 6;
    int lm = lane & 15, lg = lane >> 4;
    int wf0 = wv * 64;

    f32x4 acc[4][2];
#pragma unroll
    for (int a = 0; a < 4; ++a)
#pragma unroll
        for (int b = 0; b < 2; ++b) acc[a][b] = (f32x4){0.f, 0.f, 0.f, 0.f};

    for (int kt = 0; kt < FIN; kt += 32) {
        bf16x8 af[4];
#pragma unroll
        for (int fi = 0; fi < 4; ++fi)
            af[fi] = *(const bf16x8*)(WbT + (wf0 + fi*16 + lm) * FIN + kt + lg*8);
        bf16x8 bfr[2];
#pragma unroll
        for (int ii = 0; ii < 2; ++ii) {
            const float* xp = x + (i0 + ii*16 + lm) * FIN + kt + lg*8;
            f32x4 v0 = *(const f32x4*)(xp);
            f32x4 v1 = *(const f32x4*)(xp + 4);
            bf16x8 b;
#pragma unroll
            for (int e = 0; e < 4; ++e) { b[e] = (__bf16)v0[e]; b[4+e] = (__bf16)v1[e]; }
            bfr[ii] = b;
        }
#pragma unroll
        for (int fi = 0; fi < 4; ++fi)
#pragma unroll
            for (int ii = 0; ii < 2; ++ii)
                acc[fi][ii] = __builtin_amdgcn_mfma_f32_16x16x32_bf16(af[fi], bfr[ii], acc[fi][ii], 0, 0, 0);
    }
#pragma unroll
    for (int fi = 0; fi < 4; ++fi)
#pragma unroll
        for (int ii = 0; ii < 2; ++ii)
#pragma unroll
            for (int q = 0; q < 4; ++q)
                hTb[(wf0 + fi*16 + lg*4 + q) * NROW + i0 + ii*16 + lm] = (__bf16)acc[fi][ii][q];
}

// ---------------- K3a: l1,l2 ----------------
__global__ void k3_logits(const unsigned short* __restrict__ hTb_u,
                          const float* __restrict__ a1, const float* __restrict__ a2,
                          float* __restrict__ l1, float* __restrict__ l2) {
    const __bf16* hTb = (const __bf16*)hTb_u;
    int i = blockIdx.x * 256 + threadIdx.x;
    float s1 = 0.f, s2 = 0.f;
    for (int f = 0; f < FOUT; ++f) {
        float h = (float)hTb[f * NROW + i];
        s1 += h * a1[f];
        s2 += h * a2[f];
    }
    l1[i] = s1; l2[i] = s2;
}

// ---------------- K3b: mean_h ----------------
__global__ void k3_mean(const unsigned short* __restrict__ hTb_u, float* __restrict__ mean_h) {
    const __bf16* hTb = (const __bf16*)hTb_u;
    int f = blockIdx.x;
    int t = threadIdx.x;
    float s = 0.f;
    for (int i = t; i < NROW; i += 256) s += (float)hTb[f * NROW + i];
#pragma unroll
    for (int m = 1; m < 64; m <<= 1) s += __shfl_xor(s, m);
    __shared__ float red[4];
    if ((t & 63) == 0) red[t >> 6] = s;
    __syncthreads();
    if (t == 0) mean_h[f] = (red[0] + red[1] + red[2] + red[3]) * (1.0f / NROW);
}

// ---------------- K4: fused masked-softmax-weighted GEMM ----------------
// template V: 0=full, 1=no-stage (exp/LDS-write skipped), 2=no-MFMA/af (stage only), 3=af-const (no hTb loads)
template<int V>
__global__ __launch_bounds__(256, 2) void k4_attn(const int* __restrict__ adj,
                                                  const unsigned short* __restrict__ hTb_u,
                                                  const float* __restrict__ l1,
                                                  const float* __restrict__ l2,
                                                  float* __restrict__ outpT,
                                                  float* __restrict__ Zp,
                                                  int js, int jwidth, int ntiles, int rep) {
    const __bf16* hTb = (const __bf16*)hTb_u;
    __shared__ __align__(16) __bf16 wlds[2][64 * 64];

    int b = blockIdx.x;
    int js_idx = b % js;
    int it = b / js;
    int i0 = it * 64;
    int jstart = js_idx * jwidth;

    int t = threadIdx.x;
    int lane = t & 63, wv = t >> 6;
    int lm = lane & 15, lg = lane >> 4;
    int wf0 = wv * 64;
    int r = t >> 2, cc = t & 3;     // staging: row r (0..63), chunk cc (16 j's per thread)
    int i_glob = i0 + r;
    float l1v = l1[i_glob];

    const i32x4* adj4 = (const i32x4*)adj;
    const f32x4* l24  = (const f32x4*)l2;
    long arow = (long)i_glob * (NROW / 4);

    f32x4 acc[4][4];
#pragma unroll
    for (int a = 0; a < 4; ++a)
#pragma unroll
        for (int c = 0; c < 4; ++c) acc[a][c] = (f32x4){0.f, 0.f, 0.f, 0.f};
    float zpart = 0.f;

    i32x4 adjA[4], adjB[4];

    auto loadT = [&](i32x4 (&adjR)[4], int jb) {
        int c4 = jb >> 2;
#pragma unroll
        for (int k = 0; k < 4; ++k)
            adjR[k] = adj4[arow + c4 + cc + 4*k];
    };

    auto stageT = [&](int bufi, i32x4 (&adjR)[4], int jb) {
        if constexpr (V == 1) {
            // keep adj loads live without doing stage work (rule #17)
#pragma unroll
            for (int k = 0; k < 4; ++k)
                asm volatile("" :: "v"(adjR[k][0]), "v"(adjR[k][1]), "v"(adjR[k][2]), "v"(adjR[k][3]));
        } else {
            int c4 = jb >> 2;
            __bf16* wl = wlds[bufi];
            float zadd = 0.f;
#pragma unroll
            for (int k = 0; k < 4; ++k) {
                f32x4 l2v = l24[c4 + cc + 4*k];
                int jl = cc * 4 + 16 * k;
                bf16x4 p;
#pragma unroll
                for (int e = 0; e < 4; ++e) {
                    float s = l1v + l2v[e];
                    float ex = __expf(fmaxf(s, ALPHA * s));
                    float w = (adjR[k][e] > 0) ? ex : 0.0f;
                    __bf16 wb = (__bf16)w;
                    p[e] = wb;
                    zadd += (float)wb;   // Z consistent with bf16-rounded numerator
                }
                int blk = jl >> 3;
                int eo = r * 64 + ((blk ^ (r & 7)) << 3) + (jl & 7);   // XOR swizzle (G4)
                *(bf16x4*)(wl + eo) = p;
            }
            zpart += zadd;
        }
    };

    auto mfmaT = [&](int bufi, int jb) {
        if constexpr (V == 2) return;
        const __bf16* wl = wlds[bufi];
        bf16x8 af[2][4];
        if constexpr (V == 3) {
            __bf16 c = (__bf16)l1v;   // runtime-derived constant, same MFMA cost
#pragma unroll
            for (int ks = 0; ks < 2; ++ks)
#pragma unroll
                for (int fi = 0; fi < 4; ++fi)
                    af[ks][fi] = (bf16x8){c, c, c, c, c, c, c, c};
        } else {
#pragma unroll
            for (int ks = 0; ks < 2; ++ks)
#pragma unroll
                for (int fi = 0; fi < 4; ++fi)
                    af[ks][fi] = *(const bf16x8*)(hTb + (wf0 + fi*16 + lm) * NROW + jb + ks*32 + lg*8);
        }
#pragma unroll
        for (int ks = 0; ks < 2; ++ks) {
            bf16x8 bw[4];
#pragma unroll
            for (int ii = 0; ii < 4; ++ii) {
                int row = ii * 16 + lm;
                int blk = ks * 4 + lg;
                bw[ii] = *(const bf16x8*)(wl + row * 64 + ((blk ^ (row & 7)) << 3));
            }
#pragma unroll
            for (int fi = 0; fi < 4; ++fi)
#pragma unroll
                for (int ii = 0; ii < 4; ++ii)
                    acc[fi][ii] = __builtin_amdgcn_mfma_f32_16x16x32_bf16(af[ks][fi], bw[ii], acc[fi][ii], 0, 0, 0);
        }
    };

    // pipeline: 1 barrier/tile; adj register-prefetched 2 tiles deep
    for (int rp = 0; rp < rep; ++rp) {
        loadT(adjA, jstart);
        stageT(0, adjA, jstart);
        loadT(adjB, jstart + 64);
        __syncthreads();
        for (int tt = 0; tt < ntiles; tt += 2) {
            if (tt + 2 < ntiles) loadT(adjA, jstart + (tt + 2) * 64);
            stageT(1, adjB, jstart + (tt + 1) * 64);
            mfmaT(0, jstart + tt * 64);
            __syncthreads();
            if (tt + 3 < ntiles) loadT(adjB, jstart + (tt + 3) * 64);
            if (tt + 2 < ntiles) stageT(0, adjA, jstart + (tt + 2) * 64);  // guarded: no double-Z (r7 bug)
            mfmaT(1, jstart + (tt + 1) * 64);
            __syncthreads();
        }
    }

    // Z row-reduce over the 4 staging threads per row
    float zs = zpart + __shfl_xor(zpart, 1);
    zs += __shfl_xor(zs, 2);
    if (cc == 0) Zp[js_idx * NROW + i_glob] = zs;

    // store transposed partials: outpT[js][f][i]
#pragma unroll
    for (int fi = 0; fi < 4; ++fi)
#pragma unroll
        for (int ii = 0; ii < 4; ++ii)
#pragma unroll
            for (int q = 0; q < 4; ++q)
                outpT[(long)js_idx * (NROW * FOUT) + (wf0 + fi*16 + lg*4 + q) * NROW + i0 + ii*16 + lm] = acc[fi][ii][q];
}

// ---------------- K5: combine partials + global term + softmax div + elu + transpose ----------------
__global__ void k5_final(const float* __restrict__ outpT, const float* __restrict__ Zp,
                         const float* __restrict__ l1, const float* __restrict__ mean_h,
                         const float* __restrict__ a2, float* __restrict__ out, int js) {
    __shared__ float tile[64][65];
    __shared__ float red[4];
    __shared__ float s_mda2;
    int b = blockIdx.x;
    int it = b >> 2, ft = b & 3;
    int i0 = it * 64, f0 = ft * 64;
    int t = threadIdx.x;

    float v = mean_h[t] * a2[t];
#pragma unroll
    for (int m = 1; m < 64; m <<= 1) v += __shfl_xor(v, m);
    if ((t & 63) == 0) red[t >> 6] = v;
    __syncthreads();
    if (t == 0) s_mda2 = red[0] + red[1] + red[2] + red[3];

    {
        int fl = t >> 2, icb = (t & 3) * 16;
#pragma unroll
        for (int c = 0; c < 4; ++c) {
            f32x4 vv = (f32x4){0.f, 0.f, 0.f, 0.f};
            for (int s = 0; s < js; ++s) {
                f32x4 u = *(const f32x4*)(outpT + (long)s * (NROW * FOUT) + (f0 + fl) * NROW + i0 + icb + 4*c);
                vv += u;
            }
#pragma unroll
            for (int e = 0; e < 4; ++e) tile[fl][icb + 4*c + e] = vv[e];
        }
    }
    __syncthreads();
    int il = t >> 2, fcb = (t & 3) * 16;
    int i = i0 + il;
    float g = l1[i] + s_mda2;
    float egi = __expf(fmaxf(g, ALPHA * g));
    float z = egi;
    for (int s = 0; s < js; ++s) z += Zp[s * NROW + i];
#pragma unroll
    for (int c = 0; c < 4; ++c) {
        f32x4 o;
#pragma unroll
        for (int e = 0; e < 4; ++e) {
            int fl = fcb + 4*c + e;
            float num = tile[fl][il] + egi * mean_h[f0 + fl];
            float val = num / z;
            o[e] = val > 0.f ? val : (__expf(val) - 1.0f);
        }
        *(f32x4*)(out + (long)i * FOUT + f0 + fcb + 4*c) = o;
    }
}

// ---------------- host ----------------
extern "C" void kernel_launch(void* const* d_in, const int* in_sizes, int n_in,
                              void* d_out, int out_size, void* d_ws, size_t ws_size,
                              hipStream_t stream) {
    const float* x   = (const float*)d_in[0];
    const int*   adj = (const int*)d_in[1];
    const float* W   = (const float*)d_in[2];
    const float* a1  = (const float*)d_in[3];
    const float* a2  = (const float*)d_in[4];
    float* out = (float*)d_out;
    char* ws = (char*)d_ws;

    unsigned short* hTb = (unsigned short*)(ws);                 // 4 MB
    unsigned short* WbT = (unsigned short*)(ws + 4194304);       // 256 KB
    float* l1     = (float*)(ws + 4456448);                      // 32 KB
    float* l2     = (float*)(ws + 4489216);                      // 32 KB
    float* mean_h = (float*)(ws + 4521984);                      // 1 KB
    float* Zp     = (float*)(ws + 4523008);                      // up to 256 KB
    float* outpT  = (float*)(ws + 4785152);                      // js * 8 MB

    size_t base = 4785152;
    size_t part = (size_t)NROW * FOUT * 4;
    int js = 1;
    if      (ws_size >= base + 4 * part) js = 4;
    else if (ws_size >= base + 2 * part) js = 2;
    int jwidth = NROW / js;
    int ntiles = jwidth / 64;   // js=4 -> 32 (even)

    hipLaunchKernelGGL(k1_wt,      dim3(128),      dim3(256), 0, stream, W, WbT);
    hipLaunchKernelGGL(k2_gemm1,   dim3(256),      dim3(256), 0, stream, x, WbT, hTb);
    hipLaunchKernelGGL(k3_logits,  dim3(32),       dim3(256), 0, stream, hTb, a1, a2, l1, l2);
    hipLaunchKernelGGL(k3_mean,    dim3(256),      dim3(256), 0, stream, hTb, mean_h);
    hipLaunchKernelGGL(k4_attn<0>, dim3(128 * js), dim3(256), 0, stream, adj, hTb, l1, l2, outpT, Zp, js, jwidth, ntiles, 1);
    hipLaunchKernelGGL(k5_final,   dim3(512),      dim3(256), 0, stream, outpT, Zp, l1, mean_h, a2, out, js);

    // ---- ablation round (MEASUREMENT): full ntiles, rep=2 so each variant exceeds the
    //      ~152 us fillBuffer floor and lands in the rocprof top-5. Writes only to
    //      outpT/Zp, which are dead after k5 and fully rewritten each replay. ----
    hipLaunchKernelGGL(k4_attn<0>, dim3(128 * js), dim3(256), 0, stream, adj, hTb, l1, l2, outpT, Zp, js, jwidth, ntiles, 2);
    hipLaunchKernelGGL(k4_attn<1>, dim3(128 * js), dim3(256), 0, stream, adj, hTb, l1, l2, outpT, Zp, js, jwidth, ntiles, 2);
    hipLaunchKernelGGL(k4_attn<2>, dim3(128 * js), dim3(256), 0, stream, adj, hTb, l1, l2, outpT, Zp, js, jwidth, ntiles, 2);
    hipLaunchKernelGGL(k4_attn<3>, dim3(128 * js), dim3(256), 0, stream, adj, hTb, l1, l2, outpT, Zp, js, jwidth, ntiles, 2);
}

// Round 9
// 372.749 us; speedup vs baseline: 2.1563x; 2.1563x over previous
//
#include <hip/hip_runtime.h>

#define NROW 8192
#define FIN  512
#define FOUT 256
#define ALPHA 0.2f

typedef float  f32x4  __attribute__((ext_vector_type(4)));
typedef int    i32x4  __attribute__((ext_vector_type(4)));
typedef __bf16 bf16x8 __attribute__((ext_vector_type(8)));

// ---------------- K1: WbT[f][k] = bf16(W[k][f]) ----------------
__global__ void k1_wt(const float* __restrict__ W, unsigned short* __restrict__ WbT_u) {
    __bf16* WbT = (__bf16*)WbT_u;
    __shared__ float tw[32][33];
    int bx = blockIdx.x & 7;
    int by = blockIdx.x >> 3;
    int f0 = bx * 32, k0 = by * 32;
    int tx = threadIdx.x & 31, ty = threadIdx.x >> 5;
#pragma unroll
    for (int r = 0; r < 4; ++r)
        tw[ty + 8*r][tx] = W[(k0 + ty + 8*r) * FOUT + f0 + tx];
    __syncthreads();
#pragma unroll
    for (int r = 0; r < 4; ++r)
        WbT[(f0 + ty + 8*r) * FIN + k0 + tx] = (__bf16)tw[tx][ty + 8*r];
}

// ---------------- K2: hT[f][i] = sum_k WT[f][k] * x[i][k]  (bf16 MFMA) ----------------
__global__ __launch_bounds__(256, 2) void k2_gemm1(const float* __restrict__ x,
                                                   const unsigned short* __restrict__ WbT_u,
                                                   unsigned short* __restrict__ hTb_u) {
    const __bf16* WbT = (const __bf16*)WbT_u;
    __bf16* hTb = (__bf16*)hTb_u;
    int i0 = blockIdx.x * 32;
    int t = threadIdx.x;
    int lane = t & 63, wv = t >> 6;
    int lm = lane & 15, lg = lane >> 4;
    int wf0 = wv * 64;

    f32x4 acc[4][2];
#pragma unroll
    for (int a = 0; a < 4; ++a)
#pragma unroll
        for (int b = 0; b < 2; ++b) acc[a][b] = (f32x4){0.f, 0.f, 0.f, 0.f};

    for (int kt = 0; kt < FIN; kt += 32) {
        bf16x8 af[4];
#pragma unroll
        for (int fi = 0; fi < 4; ++fi)
            af[fi] = *(const bf16x8*)(WbT + (wf0 + fi*16 + lm) * FIN + kt + lg*8);
        bf16x8 bfr[2];
#pragma unroll
        for (int ii = 0; ii < 2; ++ii) {
            const float* xp = x + (i0 + ii*16 + lm) * FIN + kt + lg*8;
            f32x4 v0 = *(const f32x4*)(xp);
            f32x4 v1 = *(const f32x4*)(xp + 4);
            bf16x8 b;
#pragma unroll
            for (int e = 0; e < 4; ++e) { b[e] = (__bf16)v0[e]; b[4+e] = (__bf16)v1[e]; }
            bfr[ii] = b;
        }
#pragma unroll
        for (int fi = 0; fi < 4; ++fi)
#pragma unroll
            for (int ii = 0; ii < 2; ++ii)
                acc[fi][ii] = __builtin_amdgcn_mfma_f32_16x16x32_bf16(af[fi], bfr[ii], acc[fi][ii], 0, 0, 0);
    }
#pragma unroll
    for (int fi = 0; fi < 4; ++fi)
#pragma unroll
        for (int ii = 0; ii < 2; ++ii)
#pragma unroll
            for (int q = 0; q < 4; ++q)
                hTb[(wf0 + fi*16 + lg*4 + q) * NROW + i0 + ii*16 + lm] = (__bf16)acc[fi][ii][q];
}

// ---------------- K3a: l1,l2 ----------------
__global__ void k3_logits(const unsigned short* __restrict__ hTb_u,
                          const float* __restrict__ a1, const float* __restrict__ a2,
                          float* __restrict__ l1, float* __restrict__ l2) {
    const __bf16* hTb = (const __bf16*)hTb_u;
    int i = blockIdx.x * 256 + threadIdx.x;
    float s1 = 0.f, s2 = 0.f;
    for (int f = 0; f < FOUT; ++f) {
        float h = (float)hTb[f * NROW + i];
        s1 += h * a1[f];
        s2 += h * a2[f];
    }
    l1[i] = s1; l2[i] = s2;
}

// ---------------- K3b: mean_h ----------------
__global__ void k3_mean(const unsigned short* __restrict__ hTb_u, float* __restrict__ mean_h) {
    const __bf16* hTb = (const __bf16*)hTb_u;
    int f = blockIdx.x;
    int t = threadIdx.x;
    float s = 0.f;
    for (int i = t; i < NROW; i += 256) s += (float)hTb[f * NROW + i];
#pragma unroll
    for (int m = 1; m < 64; m <<= 1) s += __shfl_xor(s, m);
    __shared__ float red[4];
    if ((t & 63) == 0) red[t >> 6] = s;
    __syncthreads();
    if (t == 0) mean_h[f] = (red[0] + red[1] + red[2] + red[3]) * (1.0f / NROW);
}

// ---------------- K4: wave-autonomous fused masked-softmax-weighted GEMM ----------------
// Zero barriers, zero LDS. Each wave owns a 16-row i-tile x 1 j-split.
// B-fragment (w) computed per-lane directly in MFMA layout: lane = (lm=i-col, lg=j-chunk).
__global__ __launch_bounds__(256, 2) void k4_wave(const int* __restrict__ adj,
                                                  const unsigned short* __restrict__ hTb_u,
                                                  const float* __restrict__ l1,
                                                  const float* __restrict__ l2,
                                                  float* __restrict__ outpT,
                                                  float* __restrict__ Zp,
                                                  int js, int jwidth) {
    const __bf16* hTb = (const __bf16*)hTb_u;
    int wv = threadIdx.x >> 6, lane = threadIdx.x & 63;
    int jsx = blockIdx.x % js;
    int ib  = blockIdx.x / js;
    int it  = ib * 4 + wv;          // 0..511 — wave's 16-row i-tile
    int i0w = it * 16;
    int jstart = jsx * jwidth;
    int nsteps = jwidth / 32;       // js=4 -> 64 (even)
    int lm = lane & 15, lg = lane >> 4;
    float l1v = l1[i0w + lm];

    const int* arow = adj + (long)(i0w + lm) * NROW;   // per-lane adj row base

    f32x4 acc[16];
#pragma unroll
    for (int fi = 0; fi < 16; ++fi) acc[fi] = (f32x4){0.f, 0.f, 0.f, 0.f};
    float zpart = 0.f;

    // depth-2 prefetch, named buffers (rule #20: no runtime-indexed arrays)
    i32x4 aA0, aA1, aB0, aB1;
    f32x4 lA0, lA1, lB0, lB1;

    auto LOAD = [&](int j0, i32x4& a0, i32x4& a1, f32x4& b0, f32x4& b1) {
        const i32x4* ap = (const i32x4*)(arow + j0 + lg*8);
        a0 = ap[0]; a1 = ap[1];
        const f32x4* lp = (const f32x4*)(l2 + j0 + lg*8);
        b0 = lp[0]; b1 = lp[1];
    };
    auto STEP = [&](int j0, i32x4 a0, i32x4 a1, f32x4 b0, f32x4 b1) {
        bf16x8 wfrag;
        float zadd = 0.f;
#pragma unroll
        for (int e = 0; e < 4; ++e) {
            float s = l1v + b0[e];
            float ex = __expf(fmaxf(s, ALPHA * s));
            float w = (a0[e] > 0) ? ex : 0.f;
            __bf16 wb = (__bf16)w;
            wfrag[e] = wb; zadd += (float)wb;     // Z consistent with bf16-rounded numerator
        }
#pragma unroll
        for (int e = 0; e < 4; ++e) {
            float s = l1v + b1[e];
            float ex = __expf(fmaxf(s, ALPHA * s));
            float w = (a1[e] > 0) ? ex : 0.f;
            __bf16 wb = (__bf16)w;
            wfrag[4 + e] = wb; zadd += (float)wb;
        }
        zpart += zadd;
        const __bf16* hp = hTb + (long)lm * NROW + j0 + lg*8;
#pragma unroll
        for (int fi = 0; fi < 16; ++fi) {
            bf16x8 af = *(const bf16x8*)(hp + fi * (16 * NROW));
            acc[fi] = __builtin_amdgcn_mfma_f32_16x16x32_bf16(af, wfrag, acc[fi], 0, 0, 0);
        }
    };

    LOAD(jstart,      aA0, aA1, lA0, lA1);
    LOAD(jstart + 32, aB0, aB1, lB0, lB1);
    for (int s = 0; s < nsteps; s += 2) {
        int j0 = jstart + s * 32;
        STEP(j0, aA0, aA1, lA0, lA1);
        int jpA = (s + 2 < nsteps) ? j0 + 64 : jstart;    // tail: dead reload, never consumed
        LOAD(jpA, aA0, aA1, lA0, lA1);
        STEP(j0 + 32, aB0, aB1, lB0, lB1);
        int jpB = (s + 3 < nsteps) ? j0 + 96 : jstart;
        LOAD(jpB, aB0, aB1, lB0, lB1);
    }

    // Z: row i's weights live in lanes {lm, lm+16, lm+32, lm+48}
    float zs = zpart + __shfl_xor(zpart, 16);
    zs += __shfl_xor(zs, 32);
    if (lg == 0) Zp[jsx * NROW + i0w + lm] = zs;

    // D layout (m89): row f = fi*16 + lg*4 + q, col i = lm
    float* op = outpT + (long)jsx * (NROW * FOUT);
#pragma unroll
    for (int fi = 0; fi < 16; ++fi)
#pragma unroll
        for (int q = 0; q < 4; ++q)
            op[(fi*16 + lg*4 + q) * NROW + i0w + lm] = acc[fi][q];
}

// ---------------- K5: combine partials + global term + softmax div + elu + transpose ----------------
__global__ void k5_final(const float* __restrict__ outpT, const float* __restrict__ Zp,
                         const float* __restrict__ l1, const float* __restrict__ mean_h,
                         const float* __restrict__ a2, float* __restrict__ out, int js) {
    __shared__ float tile[64][65];
    __shared__ float red[4];
    __shared__ float s_mda2;
    int b = blockIdx.x;
    int it = b >> 2, ft = b & 3;
    int i0 = it * 64, f0 = ft * 64;
    int t = threadIdx.x;

    float v = mean_h[t] * a2[t];
#pragma unroll
    for (int m = 1; m < 64; m <<= 1) v += __shfl_xor(v, m);
    if ((t & 63) == 0) red[t >> 6] = v;
    __syncthreads();
    if (t == 0) s_mda2 = red[0] + red[1] + red[2] + red[3];

    {
        int fl = t >> 2, icb = (t & 3) * 16;
#pragma unroll
        for (int c = 0; c < 4; ++c) {
            f32x4 vv = (f32x4){0.f, 0.f, 0.f, 0.f};
            for (int s = 0; s < js; ++s) {
                f32x4 u = *(const f32x4*)(outpT + (long)s * (NROW * FOUT) + (f0 + fl) * NROW + i0 + icb + 4*c);
                vv += u;
            }
#pragma unroll
            for (int e = 0; e < 4; ++e) tile[fl][icb + 4*c + e] = vv[e];
        }
    }
    __syncthreads();
    int il = t >> 2, fcb = (t & 3) * 16;
    int i = i0 + il;
    float g = l1[i] + s_mda2;
    float egi = __expf(fmaxf(g, ALPHA * g));
    float z = egi;
    for (int s = 0; s < js; ++s) z += Zp[s * NROW + i];
#pragma unroll
    for (int c = 0; c < 4; ++c) {
        f32x4 o;
#pragma unroll
        for (int e = 0; e < 4; ++e) {
            int fl = fcb + 4*c + e;
            float num = tile[fl][il] + egi * mean_h[f0 + fl];
            float val = num / z;
            o[e] = val > 0.f ? val : (__expf(val) - 1.0f);
        }
        *(f32x4*)(out + (long)i * FOUT + f0 + fcb + 4*c) = o;
    }
}

// ---------------- host ----------------
extern "C" void kernel_launch(void* const* d_in, const int* in_sizes, int n_in,
                              void* d_out, int out_size, void* d_ws, size_t ws_size,
                              hipStream_t stream) {
    const float* x   = (const float*)d_in[0];
    const int*   adj = (const int*)d_in[1];
    const float* W   = (const float*)d_in[2];
    const float* a1  = (const float*)d_in[3];
    const float* a2  = (const float*)d_in[4];
    float* out = (float*)d_out;
    char* ws = (char*)d_ws;

    unsigned short* hTb = (unsigned short*)(ws);                 // 4 MB
    unsigned short* WbT = (unsigned short*)(ws + 4194304);       // 256 KB
    float* l1     = (float*)(ws + 4456448);                      // 32 KB
    float* l2     = (float*)(ws + 4489216);                      // 32 KB
    float* mean_h = (float*)(ws + 4521984);                      // 1 KB
    float* Zp     = (float*)(ws + 4523008);                      // up to 256 KB
    float* outpT  = (float*)(ws + 4785152);                      // js * 8 MB

    size_t base = 4785152;
    size_t part = (size_t)NROW * FOUT * 4;
    int js = 1;
    if      (ws_size >= base + 4 * part) js = 4;
    else if (ws_size >= base + 2 * part) js = 2;
    int jwidth = NROW / js;

    hipLaunchKernelGGL(k1_wt,     dim3(128),      dim3(256), 0, stream, W, WbT);
    hipLaunchKernelGGL(k2_gemm1,  dim3(256),      dim3(256), 0, stream, x, WbT, hTb);
    hipLaunchKernelGGL(k3_logits, dim3(32),       dim3(256), 0, stream, hTb, a1, a2, l1, l2);
    hipLaunchKernelGGL(k3_mean,   dim3(256),      dim3(256), 0, stream, hTb, mean_h);
    hipLaunchKernelGGL(k4_wave,   dim3(128 * js), dim3(256), 0, stream, adj, hTb, l1, l2, outpT, Zp, js, jwidth);
    hipLaunchKernelGGL(k5_final,  dim3(512),      dim3(256), 0, stream, outpT, Zp, l1, mean_h, a2, out, js);
}

// Round 10
// 355.177 us; speedup vs baseline: 2.2630x; 1.0495x over previous
//
#include <hip/hip_runtime.h>

#define NROW 8192
#define FIN  512
#define FOUT 256
#define ALPHA 0.2f

typedef float  f32x4  __attribute__((ext_vector_type(4)));
typedef int    i32x4  __attribute__((ext_vector_type(4)));
typedef __bf16 bf16x8 __attribute__((ext_vector_type(8)));
typedef unsigned long long u64;

// ---------------- K0: compress adj (int32 0/1) -> row-major u64 bitmask, streams at HBM BW ----------------
__global__ __launch_bounds__(256) void k0_bits(const int* __restrict__ adj, u64* __restrict__ bits) {
    const long total = (long)NROW * (NROW / 64);          // 1,048,576 words
    int gw = (blockIdx.x * 256 + threadIdx.x) >> 6;       // global wave id
    int lane = threadIdx.x & 63;
    int nw = (gridDim.x * 256) >> 6;
    for (long wb = (long)gw * 4; wb < total; wb += (long)nw * 4) {
        int v0 = adj[(wb + 0) * 64 + lane];
        int v1 = adj[(wb + 1) * 64 + lane];
        int v2 = adj[(wb + 2) * 64 + lane];
        int v3 = adj[(wb + 3) * 64 + lane];
        u64 m0 = __ballot(v0 > 0);
        u64 m1 = __ballot(v1 > 0);
        u64 m2 = __ballot(v2 > 0);
        u64 m3 = __ballot(v3 > 0);
        if (lane == 0) {
            bits[wb + 0] = m0; bits[wb + 1] = m1;
            bits[wb + 2] = m2; bits[wb + 3] = m3;
        }
    }
}

// ---------------- K1: WbT[f][k] = bf16(W[k][f]) ----------------
__global__ void k1_wt(const float* __restrict__ W, unsigned short* __restrict__ WbT_u) {
    __bf16* WbT = (__bf16*)WbT_u;
    __shared__ float tw[32][33];
    int bx = blockIdx.x & 7;
    int by = blockIdx.x >> 3;
    int f0 = bx * 32, k0 = by * 32;
    int tx = threadIdx.x & 31, ty = threadIdx.x >> 5;
#pragma unroll
    for (int r = 0; r < 4; ++r)
        tw[ty + 8*r][tx] = W[(k0 + ty + 8*r) * FOUT + f0 + tx];
    __syncthreads();
#pragma unroll
    for (int r = 0; r < 4; ++r)
        WbT[(f0 + ty + 8*r) * FIN + k0 + tx] = (__bf16)tw[tx][ty + 8*r];
}

// ---------------- K2: h = x@W; writes hTb[f][i] (for k3) AND hP packed A-frag layout (for k4) ----------------
// hP element order: for f-block fb (16 f's) and j32 (32 cols): lane L = (f&15) + 16*((j&31)>>3)
// holds 8 consecutive j's -> one wave dwordx4 load = contiguous 1 KB fragment.
__global__ __launch_bounds__(256, 2) void k2_gemm1(const float* __restrict__ x,
                                                   const unsigned short* __restrict__ WbT_u,
                                                   unsigned short* __restrict__ hTb_u,
                                                   unsigned short* __restrict__ hP_u) {
    const __bf16* WbT = (const __bf16*)WbT_u;
    __bf16* hTb = (__bf16*)hTb_u;
    __bf16* hP  = (__bf16*)hP_u;
    int i0 = blockIdx.x * 32;
    int t = threadIdx.x;
    int lane = t & 63, wv = t >> 6;
    int lm = lane & 15, lg = lane >> 4;
    int wf0 = wv * 64;

    f32x4 acc[4][2];
#pragma unroll
    for (int a = 0; a < 4; ++a)
#pragma unroll
        for (int b = 0; b < 2; ++b) acc[a][b] = (f32x4){0.f, 0.f, 0.f, 0.f};

    for (int kt = 0; kt < FIN; kt += 32) {
        bf16x8 af[4];
#pragma unroll
        for (int fi = 0; fi < 4; ++fi)
            af[fi] = *(const bf16x8*)(WbT + (wf0 + fi*16 + lm) * FIN + kt + lg*8);
        bf16x8 bfr[2];
#pragma unroll
        for (int ii = 0; ii < 2; ++ii) {
            const float* xp = x + (i0 + ii*16 + lm) * FIN + kt + lg*8;
            f32x4 v0 = *(const f32x4*)(xp);
            f32x4 v1 = *(const f32x4*)(xp + 4);
            bf16x8 b;
#pragma unroll
            for (int e = 0; e < 4; ++e) { b[e] = (__bf16)v0[e]; b[4+e] = (__bf16)v1[e]; }
            bfr[ii] = b;
        }
#pragma unroll
        for (int fi = 0; fi < 4; ++fi)
#pragma unroll
            for (int ii = 0; ii < 2; ++ii)
                acc[fi][ii] = __builtin_amdgcn_mfma_f32_16x16x32_bf16(af[fi], bfr[ii], acc[fi][ii], 0, 0, 0);
    }
    // D layout (m89): f = wf0+fi*16+lg*4+q ; j(=i of h) = i0+ii*16+lm
#pragma unroll
    for (int fi = 0; fi < 4; ++fi)
#pragma unroll
        for (int ii = 0; ii < 2; ++ii)
#pragma unroll
            for (int q = 0; q < 4; ++q) {
                __bf16 v = (__bf16)acc[fi][ii][q];
                int f = wf0 + fi*16 + lg*4 + q;
                int j = i0 + ii*16 + lm;
                hTb[f * NROW + j] = v;
                int fb = f >> 4;                 // = wv*4+fi
                int ln = (f & 15) + 16 * ((j & 31) >> 3);
                hP[((long)(fb * 256 + (j >> 5))) * 512 + ln * 8 + (j & 7)] = v;
            }
}

// ---------------- K3a: l1,l2 ----------------
__global__ void k3_logits(const unsigned short* __restrict__ hTb_u,
                          const float* __restrict__ a1, const float* __restrict__ a2,
                          float* __restrict__ l1, float* __restrict__ l2) {
    const __bf16* hTb = (const __bf16*)hTb_u;
    int i = blockIdx.x * 256 + threadIdx.x;
    float s1 = 0.f, s2 = 0.f;
    for (int f = 0; f < FOUT; ++f) {
        float h = (float)hTb[f * NROW + i];
        s1 += h * a1[f];
        s2 += h * a2[f];
    }
    l1[i] = s1; l2[i] = s2;
}

// ---------------- K3b: mean_h ----------------
__global__ void k3_mean(const unsigned short* __restrict__ hTb_u, float* __restrict__ mean_h) {
    const __bf16* hTb = (const __bf16*)hTb_u;
    int f = blockIdx.x;
    int t = threadIdx.x;
    float s = 0.f;
    for (int i = t; i < NROW; i += 256) s += (float)hTb[f * NROW + i];
#pragma unroll
    for (int m = 1; m < 64; m <<= 1) s += __shfl_xor(s, m);
    __shared__ float red[4];
    if ((t & 63) == 0) red[t >> 6] = s;
    __syncthreads();
    if (t == 0) mean_h[f] = (red[0] + red[1] + red[2] + red[3]) * (1.0f / NROW);
}

// ---------------- K4: barrier-free LDS-free fused masked-softmax GEMM ----------------
// Wave = full 256 f x 16 i x jsx quarter. w computed per-lane (bits+l1+l2) directly in
// B-frag layout; af = coalesced 1KB loads from hP; 2-group register rotation.
#define MFMA4(G, BASE)                                                                   \
    acc[BASE+0] = __builtin_amdgcn_mfma_f32_16x16x32_bf16(G[0], wfrag, acc[BASE+0], 0, 0, 0); \
    acc[BASE+1] = __builtin_amdgcn_mfma_f32_16x16x32_bf16(G[1], wfrag, acc[BASE+1], 0, 0, 0); \
    acc[BASE+2] = __builtin_amdgcn_mfma_f32_16x16x32_bf16(G[2], wfrag, acc[BASE+2], 0, 0, 0); \
    acc[BASE+3] = __builtin_amdgcn_mfma_f32_16x16x32_bf16(G[3], wfrag, acc[BASE+3], 0, 0, 0);

__global__ __launch_bounds__(256, 2) void k4_stream(const u64* __restrict__ bits,
                                                    const unsigned short* __restrict__ hP_u,
                                                    const float* __restrict__ l1,
                                                    const float* __restrict__ l2,
                                                    float* __restrict__ outpT,
                                                    float* __restrict__ Zp,
                                                    int js, int jwidth) {
    const __bf16* hP = (const __bf16*)hP_u;
    int wv = threadIdx.x >> 6, lane = threadIdx.x & 63;
    int jsx = blockIdx.x % js;          // with XCD round-robin dispatch, pins jsx per XCD
    int ib  = blockIdx.x / js;
    int it  = ib * 4 + wv;
    int i0w = it * 16;
    int lm = lane & 15, lg = lane >> 4;
    int jstart = jsx * jwidth;
    int npair = jwidth / 64;
    float l1v = l1[i0w + lm];
    const u64* brow = bits + (long)(i0w + lm) * (NROW / 64);

    f32x4 acc[16];
#pragma unroll
    for (int fi = 0; fi < 16; ++fi) acc[fi] = (f32x4){0.f, 0.f, 0.f, 0.f};
    float zpart = 0.f;

    bf16x8 gA[4], gB[4];
    const long FB = 256 * 512;   // elements between consecutive f-blocks in hP

    auto AFLD = [&](bf16x8 (&g)[4], int fq, int j32) {
        const __bf16* p = hP + ((long)(fq * 4) * 256 + j32) * 512 + lane * 8;
        g[0] = *(const bf16x8*)(p);
        g[1] = *(const bf16x8*)(p + FB);
        g[2] = *(const bf16x8*)(p + 2 * FB);
        g[3] = *(const bf16x8*)(p + 3 * FB);
    };

    u64 mCur = brow[jstart >> 6];
    AFLD(gA, 0, jstart >> 5);

    for (int p = 0; p < npair; ++p) {
        int jp = jstart + p * 64;
        u64 mNext = brow[(p + 1 < npair) ? ((jp + 64) >> 6) : (jstart >> 6)];
#pragma unroll
        for (int h = 0; h < 2; ++h) {
            int j0 = jp + h * 32;
            int j32 = j0 >> 5;
            // build w fragment (per-lane: i = i0w+lm, j = j0+lg*8+e)
            f32x4 la = *(const f32x4*)(l2 + j0 + lg*8);
            f32x4 lb = *(const f32x4*)(l2 + j0 + lg*8 + 4);
            unsigned int bb = (unsigned int)(mCur >> (h * 32 + lg * 8)) & 0xffu;
            bf16x8 wfrag;
            float zadd = 0.f;
#pragma unroll
            for (int e = 0; e < 4; ++e) {
                float s = l1v + la[e];
                float ex = __expf(fmaxf(s, ALPHA * s));
                __bf16 wb = ((bb >> e) & 1u) ? (__bf16)ex : (__bf16)0.f;
                wfrag[e] = wb; zadd += (float)wb;
            }
#pragma unroll
            for (int e = 0; e < 4; ++e) {
                float s = l1v + lb[e];
                float ex = __expf(fmaxf(s, ALPHA * s));
                __bf16 wb = ((bb >> (4 + e)) & 1u) ? (__bf16)ex : (__bf16)0.f;
                wfrag[4 + e] = wb; zadd += (float)wb;
            }
            zpart += zadd;

            // rotation: load next group while MFMA'ing current
            AFLD(gB, 1, j32);
            MFMA4(gA, 0);
            AFLD(gA, 2, j32);
            MFMA4(gB, 4);
            AFLD(gB, 3, j32);
            MFMA4(gA, 8);
            int j32n = (h == 0) ? (j32 + 1)
                                : ((p + 1 < npair) ? (j32 + 1) : (jstart >> 5));
            AFLD(gA, 0, j32n);
            MFMA4(gB, 12);
        }
        mCur = mNext;
    }

    // Z: row (i0w+lm) partials live in lanes {lm, lm+16, lm+32, lm+48}
    float zs = zpart + __shfl_xor(zpart, 16);
    zs += __shfl_xor(zs, 32);
    if (lg == 0) Zp[jsx * NROW + i0w + lm] = zs;

    // D layout (m89): f = fi*16 + lg*4 + q, col i = lm
    float* op = outpT + (long)jsx * (NROW * FOUT);
#pragma unroll
    for (int fi = 0; fi < 16; ++fi)
#pragma unroll
        for (int q = 0; q < 4; ++q)
            op[(fi*16 + lg*4 + q) * NROW + i0w + lm] = acc[fi][q];
}

// ---------------- K5: combine partials + global term + softmax div + elu + transpose ----------------
__global__ void k5_final(const float* __restrict__ outpT, const float* __restrict__ Zp,
                         const float* __restrict__ l1, const float* __restrict__ mean_h,
                         const float* __restrict__ a2, float* __restrict__ out, int js) {
    __shared__ float tile[64][65];
    __shared__ float red[4];
    __shared__ float s_mda2;
    int b = blockIdx.x;
    int it = b >> 2, ft = b & 3;
    int i0 = it * 64, f0 = ft * 64;
    int t = threadIdx.x;

    float v = mean_h[t] * a2[t];
#pragma unroll
    for (int m = 1; m < 64; m <<= 1) v += __shfl_xor(v, m);
    if ((t & 63) == 0) red[t >> 6] = v;
    __syncthreads();
    if (t == 0) s_mda2 = red[0] + red[1] + red[2] + red[3];

    {
        int fl = t >> 2, icb = (t & 3) * 16;
#pragma unroll
        for (int c = 0; c < 4; ++c) {
            f32x4 vv = (f32x4){0.f, 0.f, 0.f, 0.f};
            for (int s = 0; s < js; ++s) {
                f32x4 u = *(const f32x4*)(outpT + (long)s * (NROW * FOUT) + (f0 + fl) * NROW + i0 + icb + 4*c);
                vv += u;
            }
#pragma unroll
            for (int e = 0; e < 4; ++e) tile[fl][icb + 4*c + e] = vv[e];
        }
    }
    __syncthreads();
    int il = t >> 2, fcb = (t & 3) * 16;
    int i = i0 + il;
    float g = l1[i] + s_mda2;
    float egi = __expf(fmaxf(g, ALPHA * g));
    float z = egi;
    for (int s = 0; s < js; ++s) z += Zp[s * NROW + i];
#pragma unroll
    for (int c = 0; c < 4; ++c) {
        f32x4 o;
#pragma unroll
        for (int e = 0; e < 4; ++e) {
            int fl = fcb + 4*c + e;
            float num = tile[fl][il] + egi * mean_h[f0 + fl];
            float val = num / z;
            o[e] = val > 0.f ? val : (__expf(val) - 1.0f);
        }
        *(f32x4*)(out + (long)i * FOUT + f0 + fcb + 4*c) = o;
    }
}

// ---------------- host ----------------
extern "C" void kernel_launch(void* const* d_in, const int* in_sizes, int n_in,
                              void* d_out, int out_size, void* d_ws, size_t ws_size,
                              hipStream_t stream) {
    const float* x   = (const float*)d_in[0];
    const int*   adj = (const int*)d_in[1];
    const float* W   = (const float*)d_in[2];
    const float* a1  = (const float*)d_in[3];
    const float* a2  = (const float*)d_in[4];
    float* out = (float*)d_out;
    char* ws = (char*)d_ws;

    unsigned short* hTb = (unsigned short*)(ws);                 // 4 MB  (f-major, for k3)
    unsigned short* WbT = (unsigned short*)(ws + 4194304);       // 256 KB
    float* l1     = (float*)(ws + 4456448);                      // 32 KB
    float* l2     = (float*)(ws + 4489216);                      // 32 KB
    float* mean_h = (float*)(ws + 4521984);                      // 1 KB
    float* Zp     = (float*)(ws + 4523008);                      // up to 256 KB
    u64*   bitsp  = (u64*)(ws + 4785152);                        // 8 MB bitmask
    unsigned short* hP = (unsigned short*)(ws + 13173760);       // 4 MB packed A-frags
    float* outpT  = (float*)(ws + 17368064);                     // js * 8 MB

    size_t base = 17368064;
    size_t part = (size_t)NROW * FOUT * 4;
    int js = 1;
    if      (ws_size >= base + 4 * part) js = 4;
    else if (ws_size >= base + 2 * part) js = 2;
    int jwidth = NROW / js;

    hipLaunchKernelGGL(k0_bits,   dim3(2048),              dim3(256), 0, stream, adj, bitsp);
    hipLaunchKernelGGL(k1_wt,     dim3(128),               dim3(256), 0, stream, W, WbT);
    hipLaunchKernelGGL(k2_gemm1,  dim3(256),               dim3(256), 0, stream, x, WbT, hTb, hP);
    hipLaunchKernelGGL(k3_logits, dim3(32),                dim3(256), 0, stream, hTb, a1, a2, l1, l2);
    hipLaunchKernelGGL(k3_mean,   dim3(256),               dim3(256), 0, stream, hTb, mean_h);
    hipLaunchKernelGGL(k4_stream, dim3((NROW/64) * js),    dim3(256), 0, stream, bitsp, hP, l1, l2, outpT, Zp, js, jwidth);
    hipLaunchKernelGGL(k5_final,  dim3(512),               dim3(256), 0, stream, outpT, Zp, l1, mean_h, a2, out, js);
}

// Round 11
// 191.972 us; speedup vs baseline: 4.1868x; 1.8502x over previous
//
#include <hip/hip_runtime.h>

#define NROW 8192
#define FIN  512
#define FOUT 256
#define ALPHA 0.2f

typedef float  f32x4  __attribute__((ext_vector_type(4)));
typedef int    i32x4  __attribute__((ext_vector_type(4)));
typedef __bf16 bf16x8 __attribute__((ext_vector_type(8)));
typedef __bf16 bf16x4 __attribute__((ext_vector_type(4)));

// Raw workgroup barrier WITHOUT the vmcnt(0) drain __syncthreads would emit.
// LDS writes are made visible via lgkmcnt(0); global prefetch stays in flight.
__device__ __forceinline__ void bar_lds() {
    asm volatile("s_waitcnt lgkmcnt(0)" ::: "memory");
    __builtin_amdgcn_sched_barrier(0);          // rule 18: pin the waitcnt
    __builtin_amdgcn_s_barrier();
}

// ---------------- K1: WbT[f][k] = bf16(W[k][f]) ----------------
__global__ void k1_wt(const float* __restrict__ W, unsigned short* __restrict__ WbT_u) {
    __bf16* WbT = (__bf16*)WbT_u;
    __shared__ float tw[32][33];
    int bx = blockIdx.x & 7;
    int by = blockIdx.x >> 3;
    int f0 = bx * 32, k0 = by * 32;
    int tx = threadIdx.x & 31, ty = threadIdx.x >> 5;
#pragma unroll
    for (int r = 0; r < 4; ++r)
        tw[ty + 8*r][tx] = W[(k0 + ty + 8*r) * FOUT + f0 + tx];
    __syncthreads();
#pragma unroll
    for (int r = 0; r < 4; ++r)
        WbT[(f0 + ty + 8*r) * FIN + k0 + tx] = (__bf16)tw[tx][ty + 8*r];
}

// ---------------- K2: hT[f][i] = sum_k WT[f][k] * x[i][k]  (bf16 MFMA) ----------------
__global__ __launch_bounds__(256, 2) void k2_gemm1(const float* __restrict__ x,
                                                   const unsigned short* __restrict__ WbT_u,
                                                   unsigned short* __restrict__ hTb_u) {
    const __bf16* WbT = (const __bf16*)WbT_u;
    __bf16* hTb = (__bf16*)hTb_u;
    int i0 = blockIdx.x * 32;
    int t = threadIdx.x;
    int lane = t & 63, wv = t >> 6;
    int lm = lane & 15, lg = lane >> 4;
    int wf0 = wv * 64;

    f32x4 acc[4][2];
#pragma unroll
    for (int a = 0; a < 4; ++a)
#pragma unroll
        for (int b = 0; b < 2; ++b) acc[a][b] = (f32x4){0.f, 0.f, 0.f, 0.f};

    for (int kt = 0; kt < FIN; kt += 32) {
        bf16x8 af[4];
#pragma unroll
        for (int fi = 0; fi < 4; ++fi)
            af[fi] = *(const bf16x8*)(WbT + (wf0 + fi*16 + lm) * FIN + kt + lg*8);
        bf16x8 bfr[2];
#pragma unroll
        for (int ii = 0; ii < 2; ++ii) {
            const float* xp = x + (i0 + ii*16 + lm) * FIN + kt + lg*8;
            f32x4 v0 = *(const f32x4*)(xp);
            f32x4 v1 = *(const f32x4*)(xp + 4);
            bf16x8 b;
#pragma unroll
            for (int e = 0; e < 4; ++e) { b[e] = (__bf16)v0[e]; b[4+e] = (__bf16)v1[e]; }
            bfr[ii] = b;
        }
#pragma unroll
        for (int fi = 0; fi < 4; ++fi)
#pragma unroll
            for (int ii = 0; ii < 2; ++ii)
                acc[fi][ii] = __builtin_amdgcn_mfma_f32_16x16x32_bf16(af[fi], bfr[ii], acc[fi][ii], 0, 0, 0);
    }
#pragma unroll
    for (int fi = 0; fi < 4; ++fi)
#pragma unroll
        for (int ii = 0; ii < 2; ++ii)
#pragma unroll
            for (int q = 0; q < 4; ++q)
                hTb[(wf0 + fi*16 + lg*4 + q) * NROW + i0 + ii*16 + lm] = (__bf16)acc[fi][ii][q];
}

// ---------------- K3a: l1,l2 ----------------
__global__ void k3_logits(const unsigned short* __restrict__ hTb_u,
                          const float* __restrict__ a1, const float* __restrict__ a2,
                          float* __restrict__ l1, float* __restrict__ l2) {
    const __bf16* hTb = (const __bf16*)hTb_u;
    int i = blockIdx.x * 256 + threadIdx.x;
    float s1 = 0.f, s2 = 0.f;
    for (int f = 0; f < FOUT; ++f) {
        float h = (float)hTb[f * NROW + i];
        s1 += h * a1[f];
        s2 += h * a2[f];
    }
    l1[i] = s1; l2[i] = s2;
}

// ---------------- K3b: mean_h ----------------
__global__ void k3_mean(const unsigned short* __restrict__ hTb_u, float* __restrict__ mean_h) {
    const __bf16* hTb = (const __bf16*)hTb_u;
    int f = blockIdx.x;
    int t = threadIdx.x;
    float s = 0.f;
    for (int i = t; i < NROW; i += 256) s += (float)hTb[f * NROW + i];
#pragma unroll
    for (int m = 1; m < 64; m <<= 1) s += __shfl_xor(s, m);
    __shared__ float red[4];
    if ((t & 63) == 0) red[t >> 6] = s;
    __syncthreads();
    if (t == 0) mean_h[f] = (red[0] + red[1] + red[2] + red[3]) * (1.0f / NROW);
}

// ---------------- K4: fused masked-softmax-weighted GEMM ----------------
// r8 structure + raw s_barrier (no vmcnt drain) so the depth-2 adj register
// prefetch SURVIVES phase boundaries (T3/T4 counted-vmcnt mechanism).
__global__ __launch_bounds__(256, 2) void k4_attn(const int* __restrict__ adj,
                                                  const unsigned short* __restrict__ hTb_u,
                                                  const float* __restrict__ l1,
                                                  const float* __restrict__ l2,
                                                  float* __restrict__ outpT,
                                                  float* __restrict__ Zp,
                                                  int js, int jwidth, int ntiles) {
    const __bf16* hTb = (const __bf16*)hTb_u;
    __shared__ __align__(16) __bf16 wlds[2][64 * 64];

    int b = blockIdx.x;
    int js_idx = b % js;
    int it = b / js;
    int i0 = it * 64;
    int jstart = js_idx * jwidth;

    int t = threadIdx.x;
    int lane = t & 63, wv = t >> 6;
    int lm = lane & 15, lg = lane >> 4;
    int wf0 = wv * 64;
    int r = t >> 2, cc = t & 3;     // staging: row r (0..63), chunk cc (16 j's per thread)
    int i_glob = i0 + r;
    float l1v = l1[i_glob];

    const i32x4* adj4 = (const i32x4*)adj;
    const f32x4* l24  = (const f32x4*)l2;
    long arow = (long)i_glob * (NROW / 4);

    f32x4 acc[4][4];
#pragma unroll
    for (int a = 0; a < 4; ++a)
#pragma unroll
        for (int c = 0; c < 4; ++c) acc[a][c] = (f32x4){0.f, 0.f, 0.f, 0.f};
    float zpart = 0.f;

    i32x4 adjA[4], adjB[4];

    auto loadT = [&](i32x4 (&adjR)[4], int jb) {
        int c4 = jb >> 2;
#pragma unroll
        for (int k = 0; k < 4; ++k)
            adjR[k] = adj4[arow + c4 + cc + 4*k];
    };

    auto stageT = [&](int bufi, i32x4 (&adjR)[4], int jb) {
        int c4 = jb >> 2;
        __bf16* wl = wlds[bufi];
        float zadd = 0.f;
#pragma unroll
        for (int k = 0; k < 4; ++k) {
            f32x4 l2v = l24[c4 + cc + 4*k];
            int jl = cc * 4 + 16 * k;
            bf16x4 p;
#pragma unroll
            for (int e = 0; e < 4; ++e) {
                float s = l1v + l2v[e];
                float ex = __expf(fmaxf(s, ALPHA * s));
                float w = (adjR[k][e] > 0) ? ex : 0.0f;
                __bf16 wb = (__bf16)w;
                p[e] = wb;
                zadd += (float)wb;   // Z consistent with bf16-rounded numerator
            }
            int blk = jl >> 3;
            int eo = r * 64 + ((blk ^ (r & 7)) << 3) + (jl & 7);   // XOR swizzle (G4)
            *(bf16x4*)(wl + eo) = p;
        }
        zpart += zadd;
    };

    auto mfmaT = [&](int bufi, int jb) {
        const __bf16* wl = wlds[bufi];
        bf16x8 af[2][4];
#pragma unroll
        for (int ks = 0; ks < 2; ++ks)
#pragma unroll
            for (int fi = 0; fi < 4; ++fi)
                af[ks][fi] = *(const bf16x8*)(hTb + (wf0 + fi*16 + lm) * NROW + jb + ks*32 + lg*8);
#pragma unroll
        for (int ks = 0; ks < 2; ++ks) {
            bf16x8 bw[4];
#pragma unroll
            for (int ii = 0; ii < 4; ++ii) {
                int row = ii * 16 + lm;
                int blk = ks * 4 + lg;
                bw[ii] = *(const bf16x8*)(wl + row * 64 + ((blk ^ (row & 7)) << 3));
            }
#pragma unroll
            for (int fi = 0; fi < 4; ++fi)
#pragma unroll
                for (int ii = 0; ii < 4; ++ii)
                    acc[fi][ii] = __builtin_amdgcn_mfma_f32_16x16x32_bf16(af[ks][fi], bw[ii], acc[fi][ii], 0, 0, 0);
        }
    };

    // pipeline: 1 raw barrier per tile; adj register-prefetched 2 tiles deep,
    // prefetch survives barriers (no vmcnt drain).
    loadT(adjA, jstart);
    stageT(0, adjA, jstart);
    loadT(adjB, jstart + 64);
    bar_lds();
    for (int tt = 0; tt < ntiles; tt += 2) {
        if (tt + 2 < ntiles) loadT(adjA, jstart + (tt + 2) * 64);
        stageT(1, adjB, jstart + (tt + 1) * 64);
        mfmaT(0, jstart + tt * 64);
        bar_lds();
        if (tt + 3 < ntiles) loadT(adjB, jstart + (tt + 3) * 64);
        if (tt + 2 < ntiles) stageT(0, adjA, jstart + (tt + 2) * 64);  // guarded: no double-Z
        mfmaT(1, jstart + (tt + 1) * 64);
        bar_lds();
    }

    // Z row-reduce over the 4 staging threads per row
    float zs = zpart + __shfl_xor(zpart, 1);
    zs += __shfl_xor(zs, 2);
    if (cc == 0) Zp[js_idx * NROW + i_glob] = zs;

    // store transposed partials: outpT[js][f][i]
#pragma unroll
    for (int fi = 0; fi < 4; ++fi)
#pragma unroll
        for (int ii = 0; ii < 4; ++ii)
#pragma unroll
            for (int q = 0; q < 4; ++q)
                outpT[(long)js_idx * (NROW * FOUT) + (wf0 + fi*16 + lg*4 + q) * NROW + i0 + ii*16 + lm] = acc[fi][ii][q];
}

// ---------------- K5: combine partials + global term + softmax div + elu + transpose ----------------
__global__ void k5_final(const float* __restrict__ outpT, const float* __restrict__ Zp,
                         const float* __restrict__ l1, const float* __restrict__ mean_h,
                         const float* __restrict__ a2, float* __restrict__ out, int js) {
    __shared__ float tile[64][65];
    __shared__ float red[4];
    __shared__ float s_mda2;
    int b = blockIdx.x;
    int it = b >> 2, ft = b & 3;
    int i0 = it * 64, f0 = ft * 64;
    int t = threadIdx.x;

    float v = mean_h[t] * a2[t];
#pragma unroll
    for (int m = 1; m < 64; m <<= 1) v += __shfl_xor(v, m);
    if ((t & 63) == 0) red[t >> 6] = v;
    __syncthreads();
    if (t == 0) s_mda2 = red[0] + red[1] + red[2] + red[3];

    {
        int fl = t >> 2, icb = (t & 3) * 16;
#pragma unroll
        for (int c = 0; c < 4; ++c) {
            f32x4 vv = (f32x4){0.f, 0.f, 0.f, 0.f};
            for (int s = 0; s < js; ++s) {
                f32x4 u = *(const f32x4*)(outpT + (long)s * (NROW * FOUT) + (f0 + fl) * NROW + i0 + icb + 4*c);
                vv += u;
            }
#pragma unroll
            for (int e = 0; e < 4; ++e) tile[fl][icb + 4*c + e] = vv[e];
        }
    }
    __syncthreads();
    int il = t >> 2, fcb = (t & 3) * 16;
    int i = i0 + il;
    float g = l1[i] + s_mda2;
    float egi = __expf(fmaxf(g, ALPHA * g));
    float z = egi;
    for (int s = 0; s < js; ++s) z += Zp[s * NROW + i];
#pragma unroll
    for (int c = 0; c < 4; ++c) {
        f32x4 o;
#pragma unroll
        for (int e = 0; e < 4; ++e) {
            int fl = fcb + 4*c + e;
            float num = tile[fl][il] + egi * mean_h[f0 + fl];
            float val = num / z;
            o[e] = val > 0.f ? val : (__expf(val) - 1.0f);
        }
        *(f32x4*)(out + (long)i * FOUT + f0 + fcb + 4*c) = o;
    }
}

// ---------------- host ----------------
extern "C" void kernel_launch(void* const* d_in, const int* in_sizes, int n_in,
                              void* d_out, int out_size, void* d_ws, size_t ws_size,
                              hipStream_t stream) {
    const float* x   = (const float*)d_in[0];
    const int*   adj = (const int*)d_in[1];
    const float* W   = (const float*)d_in[2];
    const float* a1  = (const float*)d_in[3];
    const float* a2  = (const float*)d_in[4];
    float* out = (float*)d_out;
    char* ws = (char*)d_ws;

    unsigned short* hTb = (unsigned short*)(ws);                 // 4 MB
    unsigned short* WbT = (unsigned short*)(ws + 4194304);       // 256 KB
    float* l1     = (float*)(ws + 4456448);                      // 32 KB
    float* l2     = (float*)(ws + 4489216);                      // 32 KB
    float* mean_h = (float*)(ws + 4521984);                      // 1 KB
    float* Zp     = (float*)(ws + 4523008);                      // up to 256 KB
    float* outpT  = (float*)(ws + 4785152);                      // js * 8 MB

    size_t base = 4785152;
    size_t part = (size_t)NROW * FOUT * 4;
    int js = 1;
    if      (ws_size >= base + 4 * part) js = 4;
    else if (ws_size >= base + 2 * part) js = 2;
    int jwidth = NROW / js;
    int ntiles = jwidth / 64;   // js=4 -> 32 (even)

    hipLaunchKernelGGL(k1_wt,     dim3(128),      dim3(256), 0, stream, W, WbT);
    hipLaunchKernelGGL(k2_gemm1,  dim3(256),      dim3(256), 0, stream, x, WbT, hTb);
    hipLaunchKernelGGL(k3_logits, dim3(32),       dim3(256), 0, stream, hTb, a1, a2, l1, l2);
    hipLaunchKernelGGL(k3_mean,   dim3(256),      dim3(256), 0, stream, hTb, mean_h);
    hipLaunchKernelGGL(k4_attn,   dim3(128 * js), dim3(256), 0, stream, adj, hTb, l1, l2, outpT, Zp, js, jwidth, ntiles);
    hipLaunchKernelGGL(k5_final,  dim3(512),      dim3(256), 0, stream, outpT, Zp, l1, mean_h, a2, out, js);
}